// Round 10
// baseline (297.349 us; speedup 1.0000x reference)
//
#include <hip/hip_runtime.h>

// x[16,4096,512] fp32 -> windows [1024, 64, 512]
//   qkv = xw @ Wqkv[512,1536]; per head (8 x 64d): S = QK^T/8, causal mask,
//   softmax, softmax AGAIN (no re-mask), out = P2 @ V; concat; @ Wproj + bproj.
//
// Pipeline: prep_weights, prep_x (pack fp16 fragments) ->
//   gemm3s<0>: Q/K cols (transposed orientation)       -> qkvP packed
//   gemm3s<1>: V cols (normal orientation)             -> qkvP packed (V^T)
//   attn_win: per-window double-softmax attention      -> hP packed
//   gemm3s<2>: out^T = Wproj^T @ hOut^T + bias         -> out fp32
//
// FP(R) packing of M[r][k], k in [0,512):
//   pos(r,k) = ((r>>4)*16 + (k>>5))*512 + (((k>>3)&3)*16 + (r&15))*8 + (k&7)
// gemm3s (R10): BK=32, 3 LDS slots (96 KB), PREFETCH DISTANCE 2, vmcnt(8).
// R8/R9 (distance 1, vmcnt(4)) stalled every iteration: slack (~1 compute
// region ~350cyc) < L2/L3 latency (~400-900cyc). Distance 2 gives ~750cyc.

typedef _Float16 f16x8 __attribute__((ext_vector_type(8)));
typedef _Float16 f16x4 __attribute__((ext_vector_type(4)));
typedef float f32x4 __attribute__((ext_vector_type(4)));

#define MFMA16(a, b, c) __builtin_amdgcn_mfma_f32_16x16x32_f16((a), (b), (c), 0, 0, 0)

__device__ __forceinline__ int swz64(int r, int c) { return r * 64 + (c ^ ((r & 7) << 3)); }
__device__ __forceinline__ int swz512(int r, int c) { return r * 512 + (c ^ ((r & 7) << 3)); }

typedef const __attribute__((address_space(1))) void* gas1_t;
typedef __attribute__((address_space(3))) void* las3_t;

// async global->LDS: 64 lanes x 16B -> 1KB chunk at wave-uniform lbase
__device__ __forceinline__ void stage16(const _Float16* g, _Float16* lbase, int lane) {
#if __has_builtin(__builtin_amdgcn_global_load_lds)
  __builtin_amdgcn_global_load_lds((gas1_t)(const void*)g, (las3_t)(void*)lbase, 16, 0, 0);
#else
  *(f16x8*)(lbase + lane * 8) = *(const f16x8*)g;
#endif
}

// ---------------------------------------------------------------------------
// prep_weights: wqkvP = FP(Wqkv^T) rows 0..1535 (Q rows scaled 0.125);
//               wprojP = FP(Wproj^T) rows 0..511.
// ---------------------------------------------------------------------------
__global__ void prep_weights(const float* __restrict__ Wqkv,
                             const float* __restrict__ Wproj,
                             _Float16* __restrict__ wqkvP,
                             _Float16* __restrict__ wprojP) {
  int idx = blockIdx.x * blockDim.x + threadIdx.x;
  if (idx < 786432) {
    int r16 = idx >> 13;
    int rem = idx & 8191;
    int kt = rem >> 9;
    int lane = (rem >> 3) & 63;
    int e = rem & 7;
    int row = r16 * 16 + (lane & 15);
    int k = kt * 32 + (lane >> 4) * 8 + e;
    float v = Wqkv[k * 1536 + row];
    if (row < 512) v *= 0.125f;
    wqkvP[idx] = (_Float16)v;
  } else {
    int j = idx - 786432;
    int r16 = j >> 13;
    int rem = j & 8191;
    int kt = rem >> 9;
    int lane = (rem >> 3) & 63;
    int e = rem & 7;
    int n = r16 * 16 + (lane & 15);
    int k = kt * 32 + (lane >> 4) * 8 + e;
    wprojP[j] = (_Float16)Wproj[k * 512 + n];
  }
}

// ---------------------------------------------------------------------------
// prep_x: xP = FP(x fp16, 65536 rows)
// ---------------------------------------------------------------------------
__global__ __launch_bounds__(512) void prep_x(const float* __restrict__ x,
                                              _Float16* __restrict__ xP) {
  __shared__ __align__(16) _Float16 sX[64 * 512];
  const int tid = threadIdx.x;
  const float4* xv = (const float4*)(x + (size_t)blockIdx.x * 32768);
#pragma unroll
  for (int it = 0; it < 8; ++it) {
    int g = tid + it * 512;
    int r = g >> 6, c0 = (g & 63) << 3;
    float4 a = xv[(r << 7) + (c0 >> 2)];
    float4 b = xv[(r << 7) + (c0 >> 2) + 1];
    f16x8 hv;
    hv[0] = (_Float16)a.x; hv[1] = (_Float16)a.y;
    hv[2] = (_Float16)a.z; hv[3] = (_Float16)a.w;
    hv[4] = (_Float16)b.x; hv[5] = (_Float16)b.y;
    hv[6] = (_Float16)b.z; hv[7] = (_Float16)b.w;
    *(f16x8*)&sX[swz512(r, c0)] = hv;
  }
  __syncthreads();
  _Float16* dst = xP + (size_t)blockIdx.x * 32768;
#pragma unroll
  for (int it = 0; it < 8; ++it) {
    int c8 = tid + it * 512;
    int rt = c8 >> 10, ks = (c8 >> 6) & 15, ln = c8 & 63;
    int row = rt * 16 + (ln & 15);
    int k0 = ks * 32 + (ln >> 4) * 8;
    f16x8 v = *(const f16x8*)&sX[swz512(row, k0)];
    *(f16x8*)(dst + c8 * 8) = v;
  }
}

// ---------------------------------------------------------------------------
// gemm3s: D[i][j] = sum_k A[i,k] B[j,k]. 256x256 tile, BK=32, K=512 (16 steps).
// 8 waves (512 thr); wave owns 128x64 (acc 8x4). LDS 96KB (3 slots).
// Iter t: stage tile t+2 -> slot (t+2)%3; vmcnt(8) (drains tile t; t+1,t+2
// stay in flight, ~2 compute regions of slack); barrier; 12 ds_read + 32 MFMA
// (setprio); lgkmcnt(0); barrier.
// MODE 0: A=Wqkv^T Q/K rows, B=tokens -> scatter Q/K to qkvP
// MODE 1: A=tokens, B=V weight rows  -> scatter V^T to qkvP
// MODE 2: A=Wproj^T rows, B=tokens   -> out fp32 + bias
// ---------------------------------------------------------------------------
template <int MODE>
__global__ __launch_bounds__(512, 2) void gemm3s(
    const _Float16* __restrict__ Afp, const _Float16* __restrict__ Bfp,
    _Float16* __restrict__ dst16, float* __restrict__ out,
    const float* __restrict__ bproj, int rTiles) {
  __shared__ __align__(16) _Float16 sG[3][2][16][512];  // 96KB
  const int tid = threadIdx.x;
  const int wid = tid >> 6;
  const int lane = tid & 63;
  const int lg = lane >> 4, lr = lane & 15;
  const int wr = wid >> 2, wc = wid & 3;
  const int wr8 = wr * 8, wc4 = wc * 4, lane8 = lane * 8;

  // XCD-chunked bijective swizzle (nwg % 8 == 0 for all modes)
  const int nwg = gridDim.x;
  const int bid = blockIdx.x;
  const int swz = (bid & 7) * (nwg >> 3) + (bid >> 3);
  const int r0 = (swz % rTiles) * 256, c0 = (swz / rTiles) * 256;

  const _Float16* Abase = Afp + (size_t)(r0 >> 4) * 8192 + lane8;
  const _Float16* Bbase = Bfp + (size_t)(c0 >> 4) * 8192 + lane8;

  const f32x4 zero4 = {0.f, 0.f, 0.f, 0.f};
  f32x4 acc[8][4];
#pragma unroll
  for (int i = 0; i < 8; ++i)
#pragma unroll
    for (int j = 0; j < 4; ++j) acc[i][j] = zero4;

  const int cs = wid * 2;  // this wave's two chunk rows
  // stage K-tile T into slot s: 4 gload_lds per wave (A x2, B x2)
  auto STAGE = [&](int s, int T) {
    stage16(Abase + (size_t)cs * 8192 + T * 512, &sG[s][0][cs][0], lane);
    stage16(Abase + (size_t)(cs + 1) * 8192 + T * 512, &sG[s][0][cs + 1][0], lane);
    stage16(Bbase + (size_t)cs * 8192 + T * 512, &sG[s][1][cs][0], lane);
    stage16(Bbase + (size_t)(cs + 1) * 8192 + T * 512, &sG[s][1][cs + 1][0], lane);
  };

  STAGE(0, 0);
  STAGE(1, 1);
  for (int t = 0; t < 16; ++t) {
    const int sl = t % 3;
    const int Tn = (t + 2 < 16) ? t + 2 : 15;  // tail re-stage: harmless
    STAGE((t + 2) % 3, Tn);                    // distance-2 prefetch
    asm volatile("s_waitcnt vmcnt(8)");  // drain tile t; t+1,t+2 in flight
    __builtin_amdgcn_s_barrier();        // publish slot sl
    __builtin_amdgcn_sched_barrier(0);
    f16x8 a[8], b[4];
#pragma unroll
    for (int mi = 0; mi < 8; ++mi)
      a[mi] = *(const f16x8*)&sG[sl][0][wr8 + mi][lane8];
#pragma unroll
    for (int ni = 0; ni < 4; ++ni)
      b[ni] = *(const f16x8*)&sG[sl][1][wc4 + ni][lane8];
    __builtin_amdgcn_s_setprio(1);
#pragma unroll
    for (int mi = 0; mi < 8; ++mi)
#pragma unroll
      for (int ni = 0; ni < 4; ++ni)
        acc[mi][ni] = MFMA16(a[mi], b[ni], acc[mi][ni]);
    __builtin_amdgcn_s_setprio(0);
    asm volatile("s_waitcnt lgkmcnt(0)");  // ds_reads of slot sl complete
    __builtin_amdgcn_sched_barrier(0);
    __builtin_amdgcn_s_barrier();          // slot sl safe to overwrite at t+1
    __builtin_amdgcn_sched_barrier(0);
  }

  // ============================ epilogue =================================
  if constexpr (MODE == 0) {
#pragma unroll
    for (int mi = 0; mi < 8; ++mi) {
      int nb = r0 + wr * 128 + mi * 16 + lg * 4;
      int sec = nb >> 9, h = (nb >> 6) & 7, db = nb & 63;
      int coff = (db >> 5) * 512 + (((db >> 3) & 3) * 16) * 8 + (db & 7);
#pragma unroll
      for (int ni = 0; ni < 4; ++ni) {
        int tg = c0 + wc * 64 + ni * 16 + lr;
        int w = tg >> 6, t = tg & 63;
        size_t pos = ((size_t)w * 24 + sec * 8 + h) * 4096 +
                     (size_t)((t >> 4) * 2) * 512 + coff + (t & 15) * 8;
        f16x4 hv;
        hv[0] = (_Float16)acc[mi][ni][0]; hv[1] = (_Float16)acc[mi][ni][1];
        hv[2] = (_Float16)acc[mi][ni][2]; hv[3] = (_Float16)acc[mi][ni][3];
        *(f16x4*)(dst16 + pos) = hv;
      }
    }
  } else if constexpr (MODE == 1) {
#pragma unroll
    for (int mi = 0; mi < 8; ++mi) {
      int tbg = r0 + wr * 128 + mi * 16 + lg * 4;
      int w = tbg >> 6, tb = tbg & 63;
      int coff = (tb >> 5) * 512 + (((tb >> 3) & 3) * 16) * 8 + (tb & 7);
#pragma unroll
      for (int ni = 0; ni < 4; ++ni) {
        int cv = c0 + wc * 64 + ni * 16 + lr;
        int h = cv >> 6, d = cv & 63;
        size_t pos = ((size_t)w * 24 + 16 + h) * 4096 +
                     (size_t)((d >> 4) * 2) * 512 + coff + (d & 15) * 8;
        f16x4 hv;
        hv[0] = (_Float16)acc[mi][ni][0]; hv[1] = (_Float16)acc[mi][ni][1];
        hv[2] = (_Float16)acc[mi][ni][2]; hv[3] = (_Float16)acc[mi][ni][3];
        *(f16x4*)(dst16 + pos) = hv;
      }
    }
  } else {
#pragma unroll
    for (int mi = 0; mi < 8; ++mi) {
      int nb = r0 + wr * 128 + mi * 16 + lg * 4;
      float4 bi = *(const float4*)&bproj[nb];
#pragma unroll
      for (int ni = 0; ni < 4; ++ni) {
        int tg = c0 + wc * 64 + ni * 16 + lr;
        float4 v;
        v.x = acc[mi][ni][0] + bi.x; v.y = acc[mi][ni][1] + bi.y;
        v.z = acc[mi][ni][2] + bi.z; v.w = acc[mi][ni][3] + bi.w;
        *(float4*)&out[(size_t)tg * 512 + nb] = v;
      }
    }
  }
}

// ---------------------------------------------------------------------------
// attn_win: 1 block = 1 window, 512 thr. 2 rounds x 4 heads; wave=(head,part).
// (verified R5)
// ---------------------------------------------------------------------------
__global__ __launch_bounds__(512, 4) void attn_win(
    const _Float16* __restrict__ qkvP, _Float16* __restrict__ hP) {
  __shared__ __align__(16) _Float16 sP[4][4096];
  const int tid = threadIdx.x;
  const int wid = tid >> 6;
  const int lane = tid & 63;
  const int lg = lane >> 4, lr = lane & 15;
  const int hl = wid >> 1, part = wid & 1;
  const int w = blockIdx.x;
  const f32x4 zero4 = {0.f, 0.f, 0.f, 0.f};

  for (int hr = 0; hr < 2; ++hr) {
    const int h = hr * 4 + hl;
    const _Float16* Qb = qkvP + ((size_t)w * 24 + h) * 4096 + lane * 8;
    const _Float16* Kb = qkvP + ((size_t)w * 24 + 8 + h) * 4096 + lane * 8;
    const _Float16* Vb = qkvP + ((size_t)w * 24 + 16 + h) * 4096 + lane * 8;

    f16x8 afq[2][2], bfk[4][2];
#pragma unroll
    for (int rs = 0; rs < 2; ++rs)
#pragma unroll
      for (int dkt = 0; dkt < 2; ++dkt)
        afq[rs][dkt] = *(const f16x8*)(Qb + ((part * 2 + rs) * 2 + dkt) * 512);
#pragma unroll
    for (int nt = 0; nt < 4; ++nt)
#pragma unroll
      for (int dkt = 0; dkt < 2; ++dkt)
        bfk[nt][dkt] = *(const f16x8*)(Kb + (nt * 2 + dkt) * 512);
    f32x4 sacc[2][4];
#pragma unroll
    for (int rs = 0; rs < 2; ++rs)
#pragma unroll
      for (int nt = 0; nt < 4; ++nt) sacc[rs][nt] = zero4;
#pragma unroll
    for (int dkt = 0; dkt < 2; ++dkt)
#pragma unroll
      for (int rs = 0; rs < 2; ++rs)
#pragma unroll
        for (int nt = 0; nt < 4; ++nt)
          sacc[rs][nt] = MFMA16(afq[rs][dkt], bfk[nt][dkt], sacc[rs][nt]);

    f16x8 afv[2][2];
#pragma unroll
    for (int ds = 0; ds < 2; ++ds)
#pragma unroll
      for (int tkt = 0; tkt < 2; ++tkt)
        afv[ds][tkt] = *(const f16x8*)(Vb + ((part * 2 + ds) * 2 + tkt) * 512);

    float p2[2][4][4];
#pragma unroll
    for (int rs = 0; rs < 2; ++rs) {
      const int rsg = part * 2 + rs;
#pragma unroll
      for (int rg = 0; rg < 4; ++rg) {
        int row = rsg * 16 + lg * 4 + rg;
        float m = -1e30f;
#pragma unroll
        for (int nt = 0; nt < 4; ++nt) {
          int col = nt * 16 + lr;
          float v = (col <= row) ? sacc[rs][nt][rg] : -1e30f;
          m = fmaxf(m, v);
        }
#pragma unroll
        for (int off = 8; off >= 1; off >>= 1) m = fmaxf(m, __shfl_xor(m, off));
        float e[4], s1 = 0.f;
#pragma unroll
        for (int nt = 0; nt < 4; ++nt) {
          int col = nt * 16 + lr;
          e[nt] = (col <= row) ? __expf(sacc[rs][nt][rg] - m) : 0.f;
          s1 += e[nt];
        }
#pragma unroll
        for (int off = 8; off >= 1; off >>= 1) s1 += __shfl_xor(s1, off);
        float inv1 = 1.f / s1;
        float e2[4], s2 = 0.f;
#pragma unroll
        for (int nt = 0; nt < 4; ++nt) {
          e2[nt] = __expf(e[nt] * inv1);
          s2 += e2[nt];
        }
#pragma unroll
        for (int off = 8; off >= 1; off >>= 1) s2 += __shfl_xor(s2, off);
        float inv2 = 1.f / s2;
#pragma unroll
        for (int nt = 0; nt < 4; ++nt) p2[rs][nt][rg] = e2[nt] * inv2;
      }
    }

#pragma unroll
    for (int rs = 0; rs < 2; ++rs) {
      const int rsg = part * 2 + rs;
#pragma unroll
      for (int nt = 0; nt < 4; ++nt) {
        int cbase = (rsg * 2 + (nt >> 1)) * 512 +
                    ((((nt * 2) + (lr >> 3)) & 3) * 16 + lg * 4) * 8 + (lr & 7);
#pragma unroll
        for (int rg = 0; rg < 4; ++rg)
          sP[hl][cbase + rg * 8] = (_Float16)p2[rs][nt][rg];
      }
    }
    __syncthreads();

    f32x4 oacc[2][4];
#pragma unroll
    for (int ds = 0; ds < 2; ++ds)
#pragma unroll
      for (int ntq = 0; ntq < 4; ++ntq) oacc[ds][ntq] = zero4;
#pragma unroll
    for (int tkt = 0; tkt < 2; ++tkt) {
      f16x8 bfp[4];
#pragma unroll
      for (int ntq = 0; ntq < 4; ++ntq)
        bfp[ntq] = *(const f16x8*)&sP[hl][(ntq * 2 + tkt) * 512 + lane * 8];
#pragma unroll
      for (int ds = 0; ds < 2; ++ds)
#pragma unroll
        for (int ntq = 0; ntq < 4; ++ntq)
          oacc[ds][ntq] = MFMA16(afv[ds][tkt], bfp[ntq], oacc[ds][ntq]);
    }

#pragma unroll
    for (int ds = 0; ds < 2; ++ds) {
      const int dsg = part * 2 + ds;
      const int e0 = (lg & 1) * 4;
      const int lgt = (dsg * 2 + (lg >> 1)) & 3;
#pragma unroll
      for (int ntq = 0; ntq < 4; ++ntq) {
        size_t pos = ((size_t)(w * 4 + ntq) * 16 + h * 2 + (dsg >> 1)) * 512 +
                     (lgt * 16 + lr) * 8 + e0;
        f16x4 hv;
        hv[0] = (_Float16)oacc[ds][ntq][0]; hv[1] = (_Float16)oacc[ds][ntq][1];
        hv[2] = (_Float16)oacc[ds][ntq][2]; hv[3] = (_Float16)oacc[ds][ntq][3];
        *(f16x4*)(hP + pos) = hv;
      }
    }
    __syncthreads();
  }
}

// ---------------------------------------------------------------------------
// Fallback (verified R2 kernel) for small workspaces: fused, 128 KB LDS.
// ---------------------------------------------------------------------------
__global__ __launch_bounds__(512, 2) void attn_fused(
    const float* __restrict__ x, const _Float16* __restrict__ wqkvP,
    const _Float16* __restrict__ wprojP, const float* __restrict__ bproj,
    float* __restrict__ out) {
  __shared__ __align__(16) _Float16 sX[64 * 512];
  __shared__ __align__(16) _Float16 sHeads[4][2][4096];

  const int tid = threadIdx.x;
  const int wid = tid >> 6;
  const int lane = tid & 63;
  const int lg = lane >> 4;
  const int lr = lane & 15;

  _Float16* sQ0 = &sHeads[0][0][0];
  _Float16* sK0 = &sHeads[1][0][0];
  _Float16* sVT0 = &sHeads[2][0][0];
  _Float16* sPO0 = &sHeads[3][0][0];

  const float4* xv = (const float4*)(x + (size_t)blockIdx.x * 32768);
#pragma unroll
  for (int it = 0; it < 8; ++it) {
    int g = tid + it * 512;
    int r = g >> 6, c0 = (g & 63) << 3;
    float4 a = xv[(r << 7) + (c0 >> 2)];
    float4 b = xv[(r << 7) + (c0 >> 2) + 1];
    f16x8 hv;
    hv[0] = (_Float16)a.x; hv[1] = (_Float16)a.y;
    hv[2] = (_Float16)a.z; hv[3] = (_Float16)a.w;
    hv[4] = (_Float16)b.x; hv[5] = (_Float16)b.y;
    hv[6] = (_Float16)b.z; hv[7] = (_Float16)b.w;
    *(f16x8*)&sX[swz512(r, c0)] = hv;
  }
  const f32x4 zero4 = {0.f, 0.f, 0.f, 0.f};
  f32x4 accO[4][4];
#pragma unroll
  for (int i = 0; i < 4; ++i)
#pragma unroll
    for (int j = 0; j < 4; ++j) accO[i][j] = zero4;
  __syncthreads();

  for (int hp = 0; hp < 4; ++hp) {
    int hu[3], su[3], stu[3];
    const _Float16* bp[3];
    f32x4 acc[3][4];
#pragma unroll
    for (int i = 0; i < 3; ++i) {
      int u = wid + 8 * i;
      int hh = u & 1, v2 = u >> 1;
      int sec = v2 % 3, strip = v2 / 3;
      hu[i] = hh; su[i] = sec; stu[i] = strip;
      int r16 = sec * 32 + (hp * 2 + hh) * 4 + strip;
      bp[i] = wqkvP + (size_t)r16 * 8192 + lane * 8;
#pragma unroll
      for (int rt = 0; rt < 4; ++rt) acc[i][rt] = zero4;
    }
    f16x8 bf[3][3];
#pragma unroll
    for (int d = 0; d < 3; ++d)
#pragma unroll
      for (int i = 0; i < 3; ++i) bf[d][i] = *(const f16x8*)(bp[i] + d * 512);
    f16x8 af[2][4];
#pragma unroll
    for (int rt = 0; rt < 4; ++rt)
      af[0][rt] = *(const f16x8*)&sX[swz512(rt * 16 + lr, lg * 8)];
#pragma unroll
    for (int ks = 0; ks < 16; ++ks) {
      if (ks < 15) {
#pragma unroll
        for (int rt = 0; rt < 4; ++rt)
          af[(ks + 1) & 1][rt] =
              *(const f16x8*)&sX[swz512(rt * 16 + lr, (ks + 1) * 32 + lg * 8)];
      }
#pragma unroll
      for (int i = 0; i < 3; ++i)
#pragma unroll
        for (int rt = 0; rt < 4; ++rt)
          acc[i][rt] = MFMA16(af[ks & 1][rt], bf[ks % 3][i], acc[i][rt]);
      if (ks + 3 < 16) {
#pragma unroll
        for (int i = 0; i < 3; ++i)
          bf[ks % 3][i] = *(const f16x8*)(bp[i] + (ks + 3) * 512);
      }
    }
#pragma unroll
    for (int i = 0; i < 3; ++i) {
      int hh = hu[i], sec = su[i], strip = stu[i];
      _Float16* dq = sQ0 + hh * 4096;
      _Float16* dk = sK0 + hh * 4096;
      _Float16* dv = sVT0 + hh * 4096;
#pragma unroll
      for (int rt = 0; rt < 4; ++rt)
#pragma unroll
        for (int rg = 0; rg < 4; ++rg) {
          int row = rt * 16 + lg * 4 + rg;
          int col = strip * 16 + lr;
          _Float16 v = (_Float16)acc[i][rt][rg];
          if (sec == 0) dq[swz64(row, col)] = v;
          else if (sec == 1) dk[swz64(row, col)] = v;
          else dv[swz64(col, row)] = v;
        }
    }
    __syncthreads();
    {
      const int hh = wid >> 2;
      const int rs = wid & 3;
      const _Float16* mQ = sQ0 + hh * 4096;
      const _Float16* mK = sK0 + hh * 4096;
      const _Float16* mV = sVT0 + hh * 4096;
      _Float16* mP = sPO0 + hh * 4096;
      f32x4 sacc[4];
#pragma unroll
      for (int nt = 0; nt < 4; ++nt) sacc[nt] = zero4;
#pragma unroll
      for (int ks = 0; ks < 2; ++ks) {
        f16x8 afq = *(const f16x8*)&mQ[swz64(rs * 16 + lr, ks * 32 + lg * 8)];
#pragma unroll
        for (int nt = 0; nt < 4; ++nt) {
          f16x8 bfk = *(const f16x8*)&mK[swz64(nt * 16 + lr, ks * 32 + lg * 8)];
          sacc[nt] = MFMA16(afq, bfk, sacc[nt]);
        }
      }
      float p2[4][4];
#pragma unroll
      for (int rg = 0; rg < 4; ++rg) {
        int row = rs * 16 + lg * 4 + rg;
        float m = -1e30f;
#pragma unroll
        for (int nt = 0; nt < 4; ++nt) {
          int col = nt * 16 + lr;
          float v = (col <= row) ? sacc[nt][rg] : -1e30f;
          m = fmaxf(m, v);
        }
#pragma unroll
        for (int off = 8; off >= 1; off >>= 1) m = fmaxf(m, __shfl_xor(m, off));
        float e[4], s1 = 0.f;
#pragma unroll
        for (int nt = 0; nt < 4; ++nt) {
          int col = nt * 16 + lr;
          e[nt] = (col <= row) ? __expf(sacc[nt][rg] - m) : 0.f;
          s1 += e[nt];
        }
#pragma unroll
        for (int off = 8; off >= 1; off >>= 1) s1 += __shfl_xor(s1, off);
        float inv1 = 1.f / s1;
        float e2[4], s2 = 0.f;
#pragma unroll
        for (int nt = 0; nt < 4; ++nt) {
          e2[nt] = __expf(e[nt] * inv1);
          s2 += e2[nt];
        }
#pragma unroll
        for (int off = 8; off >= 1; off >>= 1) s2 += __shfl_xor(s2, off);
        float inv2 = 1.f / s2;
#pragma unroll
        for (int nt = 0; nt < 4; ++nt) p2[nt][rg] = e2[nt] * inv2;
      }
#pragma unroll
      for (int nt = 0; nt < 4; ++nt)
#pragma unroll
        for (int rg = 0; rg < 4; ++rg)
          mP[swz64(rs * 16 + lg * 4 + rg, nt * 16 + lr)] = (_Float16)p2[nt][rg];
      asm volatile("" ::: "memory");
      f32x4 oacc[4];
#pragma unroll
      for (int nt = 0; nt < 4; ++nt) oacc[nt] = zero4;
#pragma unroll
      for (int ks = 0; ks < 2; ++ks) {
        f16x8 afp = *(const f16x8*)&mP[swz64(rs * 16 + lr, ks * 32 + lg * 8)];
#pragma unroll
        for (int nt = 0; nt < 4; ++nt) {
          f16x8 bfv = *(const f16x8*)&mV[swz64(nt * 16 + lr, ks * 32 + lg * 8)];
          oacc[nt] = MFMA16(afp, bfv, oacc[nt]);
        }
      }
      asm volatile("" ::: "memory");
#pragma unroll
      for (int nt = 0; nt < 4; ++nt)
#pragma unroll
        for (int rg = 0; rg < 4; ++rg)
          mP[swz64(rs * 16 + lg * 4 + rg, nt * 16 + lr)] = (_Float16)oacc[nt][rg];
    }
    __syncthreads();
    {
      f16x8 bfC[2][4], afC[2][4];
#pragma unroll
      for (int rt = 0; rt < 4; ++rt)
        afC[0][rt] = *(const f16x8*)&sPO0[swz64(rt * 16 + lr, lg * 8)];
#pragma unroll
      for (int nt = 0; nt < 4; ++nt)
        bfC[0][nt] = *(const f16x8*)(wprojP + (size_t)(wid * 4 + nt) * 8192 +
                                     (size_t)(hp * 4) * 512 + lane * 8);
#pragma unroll
      for (int g = 0; g < 4; ++g) {
        if (g < 3) {
          int hn = (g + 1) >> 1, kn = (g + 1) & 1;
#pragma unroll
          for (int rt = 0; rt < 4; ++rt)
            afC[(g + 1) & 1][rt] = *(const f16x8*)&sPO0[hn * 4096 +
                swz64(rt * 16 + lr, kn * 32 + lg * 8)];
#pragma unroll
          for (int nt = 0; nt < 4; ++nt)
            bfC[(g + 1) & 1][nt] =
                *(const f16x8*)(wprojP + (size_t)(wid * 4 + nt) * 8192 +
                                (size_t)(hp * 4 + g + 1) * 512 + lane * 8);
        }
#pragma unroll
        for (int nt = 0; nt < 4; ++nt)
#pragma unroll
          for (int rt = 0; rt < 4; ++rt)
            accO[rt][nt] = MFMA16(afC[g & 1][rt], bfC[g & 1][nt], accO[rt][nt]);
      }
    }
  }
  __syncthreads();
  float bias_r[4];
#pragma unroll
  for (int nt = 0; nt < 4; ++nt) bias_r[nt] = bproj[wid * 64 + nt * 16 + lr];
  float* sEp = (float*)&sHeads[0][0][0];
  size_t base = (size_t)blockIdx.x * 32768;
#pragma unroll
  for (int half = 0; half < 2; ++half) {
#pragma unroll
    for (int rr = 0; rr < 2; ++rr) {
      int rt = half * 2 + rr;
#pragma unroll
      for (int nt = 0; nt < 4; ++nt)
#pragma unroll
        for (int rg = 0; rg < 4; ++rg) {
          int r = rr * 16 + lg * 4 + rg;
          int c = wid * 64 + nt * 16 + lr;
          sEp[r * 512 + (c ^ (((r >> 2) & 1) << 4))] = accO[rt][nt][rg] + bias_r[nt];
        }
    }
    __syncthreads();
#pragma unroll
    for (int j = 0; j < 8; ++j) {
      int f4 = tid + j * 512;
      int r = f4 >> 7;
      int c0 = (f4 & 127) << 2;
      float4 v = *(const float4*)&sEp[r * 512 + (c0 ^ (((r >> 2) & 1) << 4))];
      *(float4*)&out[base + (size_t)(half * 32 + r) * 512 + c0] = v;
    }
    if (half == 0) __syncthreads();
  }
}

extern "C" void kernel_launch(void* const* d_in, const int* in_sizes, int n_in,
                              void* d_out, int out_size, void* d_ws, size_t ws_size,
                              hipStream_t stream) {
  const float* x = (const float*)d_in[0];
  const float* Wqkv = (const float*)d_in[1];
  const float* Wproj = (const float*)d_in[2];
  const float* bproj = (const float*)d_in[3];
  float* out = (float*)d_out;

  const size_t W1 = 786432, W2 = 262144, XN = 33554432;
  const size_t QN = 100663296, HN = 33554432;
  _Float16* wqkvP = (_Float16*)d_ws;
  _Float16* wprojP = wqkvP + W1;
  _Float16* xP = wprojP + W2;
  _Float16* qkvP = xP + XN;
  _Float16* hP = qkvP + QN;
  const size_t NEED = (W1 + W2 + XN + QN + HN) * 2;

  prep_weights<<<dim3(4096), dim3(256), 0, stream>>>(Wqkv, Wproj, wqkvP, wprojP);
  if (ws_size >= NEED) {
    prep_x<<<dim3(1024), dim3(512), 0, stream>>>(x, xP);
    // Q,K cols: A = Wqkv^T rows 0..1023 (4 row-tiles), B = tokens (256 tiles)
    gemm3s<0><<<dim3(1024), dim3(512), 0, stream>>>(wqkvP, xP, qkvP, nullptr, nullptr, 4);
    // V cols: A = tokens (256 tiles), B = V weight rows (2 tiles)
    gemm3s<1><<<dim3(512), dim3(512), 0, stream>>>(xP, wqkvP + (size_t)64 * 8192,
                                                   qkvP, nullptr, nullptr, 256);
    attn_win<<<dim3(1024), dim3(512), 0, stream>>>(qkvP, hP);
    // proj: A = Wproj^T rows (2 tiles), B = tokens (256 tiles)
    gemm3s<2><<<dim3(512), dim3(512), 0, stream>>>(wprojP, hP, nullptr, out, bproj, 2);
  } else {
    attn_fused<<<dim3(1024), dim3(512), 0, stream>>>(x, wqkvP, wprojP, bproj, out);
  }
}

// Round 11
// 291.317 us; speedup vs baseline: 1.0207x; 1.0207x over previous
//
#include <hip/hip_runtime.h>

// x[16,4096,512] fp32 -> windows [1024, 64, 512]
//   qkv = xw @ Wqkv[512,1536]; per head (8 x 64d): S = QK^T/8, causal mask,
//   softmax, softmax AGAIN (no re-mask), out = P2 @ V; concat; @ Wproj + bproj.
//
// Pipeline: prep_weights, prep_x (pack fp16 fragments) ->
//   gemm8p<0>: Q/K cols (transposed orientation)       -> qkvP packed
//   gemm8p<1>: V cols (normal orientation)             -> qkvP packed (V^T)
//   attn_win: per-window double-softmax attention      -> hP packed
//   gemm8p<2>: out^T = Wproj^T @ hOut^T + bias         -> out fp32
//
// FP(R) packing of M[r][k], k in [0,512):
//   pos(r,k) = ((r>>4)*16 + (k>>5))*512 + (((k>>3)&3)*16 + (r&15))*8 + (k&7)
//
// gemm8p (R11): BK=64, 2 slots (128KB), 4 phases/K-tile (quadrants), one
// half-tile staged per phase, vmcnt(4) at p0/p1/p3 -> every global_load_lds
// gets ~3 phases of issue-to-wait slack (true T4 counted-vmcnt; R6-R10 all
// had <=1 phase slack = de-facto drain-0, stuck at 33% MfmaUtil).
// Half-tile grouping matches quadrant consumption:
//   Ah0 = r16 {0-3,8-11} (mi 0-3 both wr), Ah1 = {4-7,12-15} (mi 4-7)
//   Bh0 = r16 {4wc+0,4wc+1} (ni 0-1),      Bh1 = {4wc+2,4wc+3} (ni 2-3)
// Issue order per tile: [Ah0, Bh0, Bh1, Ah1]; consumption p0:{Ah0,Bh0},
// p1:{Bh1}, p2:{Ah1}, p3:{}. Reads at phase p are covered by phase p-1's
// vmcnt+barrier (cross-wave visibility via barrier after every vmcnt).

typedef _Float16 f16x8 __attribute__((ext_vector_type(8)));
typedef _Float16 f16x4 __attribute__((ext_vector_type(4)));
typedef float f32x4 __attribute__((ext_vector_type(4)));

#define MFMA16(a, b, c) __builtin_amdgcn_mfma_f32_16x16x32_f16((a), (b), (c), 0, 0, 0)

__device__ __forceinline__ int swz512(int r, int c) { return r * 512 + (c ^ ((r & 7) << 3)); }
__device__ __forceinline__ int swz64(int r, int c) { return r * 64 + (c ^ ((r & 7) << 3)); }

typedef const __attribute__((address_space(1))) void* gas1_t;
typedef __attribute__((address_space(3))) void* las3_t;

__device__ __forceinline__ void stage16(const _Float16* g, _Float16* lbase, int lane) {
#if __has_builtin(__builtin_amdgcn_global_load_lds)
  __builtin_amdgcn_global_load_lds((gas1_t)(const void*)g, (las3_t)(void*)lbase, 16, 0, 0);
#else
  *(f16x8*)(lbase + lane * 8) = *(const f16x8*)g;
#endif
}

// ---------------------------------------------------------------------------
// prep_weights: wqkvP = FP(Wqkv^T) rows 0..1535 (Q rows scaled 0.125);
//               wprojP = FP(Wproj^T) rows 0..511.
// ---------------------------------------------------------------------------
__global__ void prep_weights(const float* __restrict__ Wqkv,
                             const float* __restrict__ Wproj,
                             _Float16* __restrict__ wqkvP,
                             _Float16* __restrict__ wprojP) {
  int idx = blockIdx.x * blockDim.x + threadIdx.x;
  if (idx < 786432) {
    int r16 = idx >> 13;
    int rem = idx & 8191;
    int kt = rem >> 9;
    int lane = (rem >> 3) & 63;
    int e = rem & 7;
    int row = r16 * 16 + (lane & 15);
    int k = kt * 32 + (lane >> 4) * 8 + e;
    float v = Wqkv[k * 1536 + row];
    if (row < 512) v *= 0.125f;
    wqkvP[idx] = (_Float16)v;
  } else {
    int j = idx - 786432;
    int r16 = j >> 13;
    int rem = j & 8191;
    int kt = rem >> 9;
    int lane = (rem >> 3) & 63;
    int e = rem & 7;
    int n = r16 * 16 + (lane & 15);
    int k = kt * 32 + (lane >> 4) * 8 + e;
    wprojP[j] = (_Float16)Wproj[k * 512 + n];
  }
}

// ---------------------------------------------------------------------------
// prep_x: xP = FP(x fp16, 65536 rows)
// ---------------------------------------------------------------------------
__global__ __launch_bounds__(512) void prep_x(const float* __restrict__ x,
                                              _Float16* __restrict__ xP) {
  __shared__ __align__(16) _Float16 sX[64 * 512];
  const int tid = threadIdx.x;
  const float4* xv = (const float4*)(x + (size_t)blockIdx.x * 32768);
#pragma unroll
  for (int it = 0; it < 8; ++it) {
    int g = tid + it * 512;
    int r = g >> 6, c0 = (g & 63) << 3;
    float4 a = xv[(r << 7) + (c0 >> 2)];
    float4 b = xv[(r << 7) + (c0 >> 2) + 1];
    f16x8 hv;
    hv[0] = (_Float16)a.x; hv[1] = (_Float16)a.y;
    hv[2] = (_Float16)a.z; hv[3] = (_Float16)a.w;
    hv[4] = (_Float16)b.x; hv[5] = (_Float16)b.y;
    hv[6] = (_Float16)b.z; hv[7] = (_Float16)b.w;
    *(f16x8*)&sX[swz512(r, c0)] = hv;
  }
  __syncthreads();
  _Float16* dst = xP + (size_t)blockIdx.x * 32768;
#pragma unroll
  for (int it = 0; it < 8; ++it) {
    int c8 = tid + it * 512;
    int rt = c8 >> 10, ks = (c8 >> 6) & 15, ln = c8 & 63;
    int row = rt * 16 + (ln & 15);
    int k0 = ks * 32 + (ln >> 4) * 8;
    f16x8 v = *(const f16x8*)&sX[swz512(row, k0)];
    *(f16x8*)(dst + c8 * 8) = v;
  }
}

// ---------------------------------------------------------------------------
// gemm8p: D[i][j] = sum_k A[i,k] B[j,k]. 256x256 tile, BK=64, K=512 (8 tiles).
// 8 waves; wave (wr,wc) owns 128x64 (acc 8x4). LDS 128KB = 2 slots.
// MODE 0: A=Wqkv^T Q/K rows, B=tokens -> scatter Q/K to qkvP
// MODE 1: A=tokens, B=V weight rows  -> scatter V^T to qkvP
// MODE 2: A=Wproj^T rows, B=tokens   -> out fp32 + bias
// ---------------------------------------------------------------------------
template <int MODE>
__global__ __launch_bounds__(512, 2) void gemm8p(
    const _Float16* __restrict__ Afp, const _Float16* __restrict__ Bfp,
    _Float16* __restrict__ dst16, float* __restrict__ out,
    const float* __restrict__ bproj, int rTiles) {
  __shared__ __align__(16) _Float16 sG[2][2][32][512];  // [slot][A/B][r16*2+kt][1KB]
  const int tid = threadIdx.x;
  const int wid = tid >> 6;
  const int lane = tid & 63;
  const int lg = lane >> 4, lr = lane & 15;
  const int wr = wid >> 2, wc = wid & 3;
  const int lane8 = lane * 8;

  // XCD-chunked bijective swizzle (nwg % 8 == 0 for all modes)
  const int nwg = gridDim.x;
  const int bid = blockIdx.x;
  const int swz = (bid & 7) * (nwg >> 3) + (bid >> 3);
  const int r0 = (swz % rTiles) * 256, c0 = (swz / rTiles) * 256;

  const _Float16* Abase = Afp + (size_t)(r0 >> 4) * 8192 + lane8;
  const _Float16* Bbase = Bfp + (size_t)(c0 >> 4) * 8192 + lane8;

  // per-wave stage rows for each half-tile j (j: 0=Ah0, 1=Bh0, 2=Bh1, 3=Ah1)
  const int rA0 = (wid & 3) + ((wid >> 2) << 3);       // 0-3, 8-11
  const int rA1 = rA0 + 4;                             // 4-7, 12-15
  const int rB0 = ((wid >> 1) << 2) + (wid & 1);       // 0,1,4,5,8,9,12,13
  const int rB1 = rB0 + 2;                             // 2,3,6,7,10,11,14,15

  // stage half-tile j of K-tile T into slot s (2 x global_load_lds per wave)
  auto STAGEH = [&](int s, int T, int j) {
    int ab = (j == 0 || j == 3) ? 0 : 1;
    int r16l = (j == 0) ? rA0 : (j == 3) ? rA1 : (j == 1) ? rB0 : rB1;
    const _Float16* base = ab ? Bbase : Abase;
    const _Float16* src = base + (size_t)r16l * 8192 + (size_t)T * 1024;
    stage16(src, &sG[s][ab][r16l * 2][0], lane);
    stage16(src + 512, &sG[s][ab][r16l * 2 + 1][0], lane);
  };

  const f32x4 zero4 = {0.f, 0.f, 0.f, 0.f};
  f32x4 acc[8][4];
#pragma unroll
  for (int i = 0; i < 8; ++i)
#pragma unroll
    for (int j = 0; j < 4; ++j) acc[i][j] = zero4;

  f16x8 a[4][2], b0[2][2], b1[2][2];

  // prologue: tile 0 -> slot 0 (issue order Ah0,Bh0,Bh1,Ah1); vmcnt(4) ->
  // Ah0,Bh0 complete; barrier publishes them.
  STAGEH(0, 0, 0);
  STAGEH(0, 0, 1);
  STAGEH(0, 0, 2);
  STAGEH(0, 0, 3);
  asm volatile("s_waitcnt vmcnt(4)");
  __builtin_amdgcn_s_barrier();
  __builtin_amdgcn_sched_barrier(0);

  for (int T = 0; T < 8; ++T) {
    const int s = T & 1, sn = s ^ 1;
    const int Tn = (T + 1 < 8) ? T + 1 : 7;  // tail re-stage: harmless
    // ---- p0: q00 (mi0-3 x ni0-1) ----
#pragma unroll
    for (int mi = 0; mi < 4; ++mi)
#pragma unroll
      for (int kt = 0; kt < 2; ++kt)
        a[mi][kt] = *(const f16x8*)&sG[s][0][(8 * wr + mi) * 2 + kt][lane8];
#pragma unroll
    for (int ni = 0; ni < 2; ++ni)
#pragma unroll
      for (int kt = 0; kt < 2; ++kt)
        b0[ni][kt] = *(const f16x8*)&sG[s][1][(4 * wc + ni) * 2 + kt][lane8];
    STAGEH(sn, Tn, 0);
    asm volatile("s_waitcnt vmcnt(4)");   // -> Bh1(T) complete for p1
    __builtin_amdgcn_s_barrier();
    asm volatile("s_waitcnt lgkmcnt(0)");
    __builtin_amdgcn_sched_barrier(0);
    __builtin_amdgcn_s_setprio(1);
#pragma unroll
    for (int kt = 0; kt < 2; ++kt)
#pragma unroll
      for (int mi = 0; mi < 4; ++mi)
#pragma unroll
        for (int ni = 0; ni < 2; ++ni)
          acc[mi][ni] = MFMA16(a[mi][kt], b0[ni][kt], acc[mi][ni]);
    __builtin_amdgcn_s_setprio(0);
    __builtin_amdgcn_s_barrier();
    // ---- p1: q01 (mi0-3 x ni2-3) ----
#pragma unroll
    for (int ni = 0; ni < 2; ++ni)
#pragma unroll
      for (int kt = 0; kt < 2; ++kt)
        b1[ni][kt] = *(const f16x8*)&sG[s][1][(4 * wc + 2 + ni) * 2 + kt][lane8];
    STAGEH(sn, Tn, 1);
    asm volatile("s_waitcnt vmcnt(4)");   // -> Ah1(T) complete for p2
    __builtin_amdgcn_s_barrier();
    asm volatile("s_waitcnt lgkmcnt(0)");
    __builtin_amdgcn_sched_barrier(0);
    __builtin_amdgcn_s_setprio(1);
#pragma unroll
    for (int kt = 0; kt < 2; ++kt)
#pragma unroll
      for (int mi = 0; mi < 4; ++mi)
#pragma unroll
        for (int ni = 0; ni < 2; ++ni)
          acc[mi][2 + ni] = MFMA16(a[mi][kt], b1[ni][kt], acc[mi][2 + ni]);
    __builtin_amdgcn_s_setprio(0);
    __builtin_amdgcn_s_barrier();
    // ---- p2: q11 (mi4-7 x ni2-3); a[] overwritten with Ah1 rows ----
#pragma unroll
    for (int mi = 0; mi < 4; ++mi)
#pragma unroll
      for (int kt = 0; kt < 2; ++kt)
        a[mi][kt] = *(const f16x8*)&sG[s][0][(8 * wr + 4 + mi) * 2 + kt][lane8];
    STAGEH(sn, Tn, 2);
    __builtin_amdgcn_s_barrier();         // no vmcnt needed this phase
    asm volatile("s_waitcnt lgkmcnt(0)");
    __builtin_amdgcn_sched_barrier(0);
    __builtin_amdgcn_s_setprio(1);
#pragma unroll
    for (int kt = 0; kt < 2; ++kt)
#pragma unroll
      for (int mi = 0; mi < 4; ++mi)
#pragma unroll
        for (int ni = 0; ni < 2; ++ni)
          acc[4 + mi][2 + ni] = MFMA16(a[mi][kt], b1[ni][kt], acc[4 + mi][2 + ni]);
    __builtin_amdgcn_s_setprio(0);
    __builtin_amdgcn_s_barrier();
    // ---- p3: q10 (mi4-7 x ni0-1); no new reads ----
    STAGEH(sn, Tn, 3);
    asm volatile("s_waitcnt vmcnt(4)");   // -> Ah0,Bh0(T+1) complete for next p0
    __builtin_amdgcn_s_barrier();
    __builtin_amdgcn_sched_barrier(0);
    __builtin_amdgcn_s_setprio(1);
#pragma unroll
    for (int kt = 0; kt < 2; ++kt)
#pragma unroll
      for (int mi = 0; mi < 4; ++mi)
#pragma unroll
        for (int ni = 0; ni < 2; ++ni)
          acc[4 + mi][ni] = MFMA16(a[mi][kt], b0[ni][kt], acc[4 + mi][ni]);
    __builtin_amdgcn_s_setprio(0);
    __builtin_amdgcn_s_barrier();
  }

  // ============================ epilogue =================================
  if constexpr (MODE == 0) {
#pragma unroll
    for (int mi = 0; mi < 8; ++mi) {
      int nb = r0 + wr * 128 + mi * 16 + lg * 4;
      int sec = nb >> 9, h = (nb >> 6) & 7, db = nb & 63;
      int coff = (db >> 5) * 512 + (((db >> 3) & 3) * 16) * 8 + (db & 7);
#pragma unroll
      for (int ni = 0; ni < 4; ++ni) {
        int tg = c0 + wc * 64 + ni * 16 + lr;
        int w = tg >> 6, t = tg & 63;
        size_t pos = ((size_t)w * 24 + sec * 8 + h) * 4096 +
                     (size_t)((t >> 4) * 2) * 512 + coff + (t & 15) * 8;
        f16x4 hv;
        hv[0] = (_Float16)acc[mi][ni][0]; hv[1] = (_Float16)acc[mi][ni][1];
        hv[2] = (_Float16)acc[mi][ni][2]; hv[3] = (_Float16)acc[mi][ni][3];
        *(f16x4*)(dst16 + pos) = hv;
      }
    }
  } else if constexpr (MODE == 1) {
#pragma unroll
    for (int mi = 0; mi < 8; ++mi) {
      int tbg = r0 + wr * 128 + mi * 16 + lg * 4;
      int w = tbg >> 6, tb = tbg & 63;
      int coff = (tb >> 5) * 512 + (((tb >> 3) & 3) * 16) * 8 + (tb & 7);
#pragma unroll
      for (int ni = 0; ni < 4; ++ni) {
        int cv = c0 + wc * 64 + ni * 16 + lr;
        int h = cv >> 6, d = cv & 63;
        size_t pos = ((size_t)w * 24 + 16 + h) * 4096 +
                     (size_t)((d >> 4) * 2) * 512 + coff + (d & 15) * 8;
        f16x4 hv;
        hv[0] = (_Float16)acc[mi][ni][0]; hv[1] = (_Float16)acc[mi][ni][1];
        hv[2] = (_Float16)acc[mi][ni][2]; hv[3] = (_Float16)acc[mi][ni][3];
        *(f16x4*)(dst16 + pos) = hv;
      }
    }
  } else {
#pragma unroll
    for (int mi = 0; mi < 8; ++mi) {
      int nb = r0 + wr * 128 + mi * 16 + lg * 4;
      float4 bi = *(const float4*)&bproj[nb];
#pragma unroll
      for (int ni = 0; ni < 4; ++ni) {
        int tg = c0 + wc * 64 + ni * 16 + lr;
        float4 v;
        v.x = acc[mi][ni][0] + bi.x; v.y = acc[mi][ni][1] + bi.y;
        v.z = acc[mi][ni][2] + bi.z; v.w = acc[mi][ni][3] + bi.w;
        *(float4*)&out[(size_t)tg * 512 + nb] = v;
      }
    }
  }
}

// ---------------------------------------------------------------------------
// attn_win: 1 block = 1 window, 512 thr. 2 rounds x 4 heads; wave=(head,part).
// (verified R5)
// ---------------------------------------------------------------------------
__global__ __launch_bounds__(512, 4) void attn_win(
    const _Float16* __restrict__ qkvP, _Float16* __restrict__ hP) {
  __shared__ __align__(16) _Float16 sP[4][4096];
  const int tid = threadIdx.x;
  const int wid = tid >> 6;
  const int lane = tid & 63;
  const int lg = lane >> 4, lr = lane & 15;
  const int hl = wid >> 1, part = wid & 1;
  const int w = blockIdx.x;
  const f32x4 zero4 = {0.f, 0.f, 0.f, 0.f};

  for (int hr = 0; hr < 2; ++hr) {
    const int h = hr * 4 + hl;
    const _Float16* Qb = qkvP + ((size_t)w * 24 + h) * 4096 + lane * 8;
    const _Float16* Kb = qkvP + ((size_t)w * 24 + 8 + h) * 4096 + lane * 8;
    const _Float16* Vb = qkvP + ((size_t)w * 24 + 16 + h) * 4096 + lane * 8;

    f16x8 afq[2][2], bfk[4][2];
#pragma unroll
    for (int rs = 0; rs < 2; ++rs)
#pragma unroll
      for (int dkt = 0; dkt < 2; ++dkt)
        afq[rs][dkt] = *(const f16x8*)(Qb + ((part * 2 + rs) * 2 + dkt) * 512);
#pragma unroll
    for (int nt = 0; nt < 4; ++nt)
#pragma unroll
      for (int dkt = 0; dkt < 2; ++dkt)
        bfk[nt][dkt] = *(const f16x8*)(Kb + (nt * 2 + dkt) * 512);
    f32x4 sacc[2][4];
#pragma unroll
    for (int rs = 0; rs < 2; ++rs)
#pragma unroll
      for (int nt = 0; nt < 4; ++nt) sacc[rs][nt] = zero4;
#pragma unroll
    for (int dkt = 0; dkt < 2; ++dkt)
#pragma unroll
      for (int rs = 0; rs < 2; ++rs)
#pragma unroll
        for (int nt = 0; nt < 4; ++nt)
          sacc[rs][nt] = MFMA16(afq[rs][dkt], bfk[nt][dkt], sacc[rs][nt]);

    f16x8 afv[2][2];
#pragma unroll
    for (int ds = 0; ds < 2; ++ds)
#pragma unroll
      for (int tkt = 0; tkt < 2; ++tkt)
        afv[ds][tkt] = *(const f16x8*)(Vb + ((part * 2 + ds) * 2 + tkt) * 512);

    float p2[2][4][4];
#pragma unroll
    for (int rs = 0; rs < 2; ++rs) {
      const int rsg = part * 2 + rs;
#pragma unroll
      for (int rg = 0; rg < 4; ++rg) {
        int row = rsg * 16 + lg * 4 + rg;
        float m = -1e30f;
#pragma unroll
        for (int nt = 0; nt < 4; ++nt) {
          int col = nt * 16 + lr;
          float v = (col <= row) ? sacc[rs][nt][rg] : -1e30f;
          m = fmaxf(m, v);
        }
#pragma unroll
        for (int off = 8; off >= 1; off >>= 1) m = fmaxf(m, __shfl_xor(m, off));
        float e[4], s1 = 0.f;
#pragma unroll
        for (int nt = 0; nt < 4; ++nt) {
          int col = nt * 16 + lr;
          e[nt] = (col <= row) ? __expf(sacc[rs][nt][rg] - m) : 0.f;
          s1 += e[nt];
        }
#pragma unroll
        for (int off = 8; off >= 1; off >>= 1) s1 += __shfl_xor(s1, off);
        float inv1 = 1.f / s1;
        float e2[4], s2 = 0.f;
#pragma unroll
        for (int nt = 0; nt < 4; ++nt) {
          e2[nt] = __expf(e[nt] * inv1);
          s2 += e2[nt];
        }
#pragma unroll
        for (int off = 8; off >= 1; off >>= 1) s2 += __shfl_xor(s2, off);
        float inv2 = 1.f / s2;
#pragma unroll
        for (int nt = 0; nt < 4; ++nt) p2[rs][nt][rg] = e2[nt] * inv2;
      }
    }

#pragma unroll
    for (int rs = 0; rs < 2; ++rs) {
      const int rsg = part * 2 + rs;
#pragma unroll
      for (int nt = 0; nt < 4; ++nt) {
        int cbase = (rsg * 2 + (nt >> 1)) * 512 +
                    ((((nt * 2) + (lr >> 3)) & 3) * 16 + lg * 4) * 8 + (lr & 7);
#pragma unroll
        for (int rg = 0; rg < 4; ++rg)
          sP[hl][cbase + rg * 8] = (_Float16)p2[rs][nt][rg];
      }
    }
    __syncthreads();

    f32x4 oacc[2][4];
#pragma unroll
    for (int ds = 0; ds < 2; ++ds)
#pragma unroll
      for (int ntq = 0; ntq < 4; ++ntq) oacc[ds][ntq] = zero4;
#pragma unroll
    for (int tkt = 0; tkt < 2; ++tkt) {
      f16x8 bfp[4];
#pragma unroll
      for (int ntq = 0; ntq < 4; ++ntq)
        bfp[ntq] = *(const f16x8*)&sP[hl][(ntq * 2 + tkt) * 512 + lane * 8];
#pragma unroll
      for (int ds = 0; ds < 2; ++ds)
#pragma unroll
        for (int ntq = 0; ntq < 4; ++ntq)
          oacc[ds][ntq] = MFMA16(afv[ds][tkt], bfp[ntq], oacc[ds][ntq]);
    }

#pragma unroll
    for (int ds = 0; ds < 2; ++ds) {
      const int dsg = part * 2 + ds;
      const int e0 = (lg & 1) * 4;
      const int lgt = (dsg * 2 + (lg >> 1)) & 3;
#pragma unroll
      for (int ntq = 0; ntq < 4; ++ntq) {
        size_t pos = ((size_t)(w * 4 + ntq) * 16 + h * 2 + (dsg >> 1)) * 512 +
                     (lgt * 16 + lr) * 8 + e0;
        f16x4 hv;
        hv[0] = (_Float16)oacc[ds][ntq][0]; hv[1] = (_Float16)oacc[ds][ntq][1];
        hv[2] = (_Float16)oacc[ds][ntq][2]; hv[3] = (_Float16)oacc[ds][ntq][3];
        *(f16x4*)(hP + pos) = hv;
      }
    }
    __syncthreads();
  }
}

// ---------------------------------------------------------------------------
// Fallback (verified R2 kernel) for small workspaces: fused, 128 KB LDS.
// ---------------------------------------------------------------------------
__global__ __launch_bounds__(512, 2) void attn_fused(
    const float* __restrict__ x, const _Float16* __restrict__ wqkvP,
    const _Float16* __restrict__ wprojP, const float* __restrict__ bproj,
    float* __restrict__ out) {
  __shared__ __align__(16) _Float16 sX[64 * 512];
  __shared__ __align__(16) _Float16 sHeads[4][2][4096];

  const int tid = threadIdx.x;
  const int wid = tid >> 6;
  const int lane = tid & 63;
  const int lg = lane >> 4;
  const int lr = lane & 15;

  _Float16* sQ0 = &sHeads[0][0][0];
  _Float16* sK0 = &sHeads[1][0][0];
  _Float16* sVT0 = &sHeads[2][0][0];
  _Float16* sPO0 = &sHeads[3][0][0];

  const float4* xv = (const float4*)(x + (size_t)blockIdx.x * 32768);
#pragma unroll
  for (int it = 0; it < 8; ++it) {
    int g = tid + it * 512;
    int r = g >> 6, c0 = (g & 63) << 3;
    float4 a = xv[(r << 7) + (c0 >> 2)];
    float4 b = xv[(r << 7) + (c0 >> 2) + 1];
    f16x8 hv;
    hv[0] = (_Float16)a.x; hv[1] = (_Float16)a.y;
    hv[2] = (_Float16)a.z; hv[3] = (_Float16)a.w;
    hv[4] = (_Float16)b.x; hv[5] = (_Float16)b.y;
    hv[6] = (_Float16)b.z; hv[7] = (_Float16)b.w;
    *(f16x8*)&sX[swz512(r, c0)] = hv;
  }
  const f32x4 zero4 = {0.f, 0.f, 0.f, 0.f};
  f32x4 accO[4][4];
#pragma unroll
  for (int i = 0; i < 4; ++i)
#pragma unroll
    for (int j = 0; j < 4; ++j) accO[i][j] = zero4;
  __syncthreads();

  for (int hp = 0; hp < 4; ++hp) {
    int hu[3], su[3], stu[3];
    const _Float16* bp[3];
    f32x4 acc[3][4];
#pragma unroll
    for (int i = 0; i < 3; ++i) {
      int u = wid + 8 * i;
      int hh = u & 1, v2 = u >> 1;
      int sec = v2 % 3, strip = v2 / 3;
      hu[i] = hh; su[i] = sec; stu[i] = strip;
      int r16 = sec * 32 + (hp * 2 + hh) * 4 + strip;
      bp[i] = wqkvP + (size_t)r16 * 8192 + lane * 8;
#pragma unroll
      for (int rt = 0; rt < 4; ++rt) acc[i][rt] = zero4;
    }
    f16x8 bf[3][3];
#pragma unroll
    for (int d = 0; d < 3; ++d)
#pragma unroll
      for (int i = 0; i < 3; ++i) bf[d][i] = *(const f16x8*)(bp[i] + d * 512);
    f16x8 af[2][4];
#pragma unroll
    for (int rt = 0; rt < 4; ++rt)
      af[0][rt] = *(const f16x8*)&sX[swz512(rt * 16 + lr, lg * 8)];
#pragma unroll
    for (int ks = 0; ks < 16; ++ks) {
      if (ks < 15) {
#pragma unroll
        for (int rt = 0; rt < 4; ++rt)
          af[(ks + 1) & 1][rt] =
              *(const f16x8*)&sX[swz512(rt * 16 + lr, (ks + 1) * 32 + lg * 8)];
      }
#pragma unroll
      for (int i = 0; i < 3; ++i)
#pragma unroll
        for (int rt = 0; rt < 4; ++rt)
          acc[i][rt] = MFMA16(af[ks & 1][rt], bf[ks % 3][i], acc[i][rt]);
      if (ks + 3 < 16) {
#pragma unroll
        for (int i = 0; i < 3; ++i)
          bf[ks % 3][i] = *(const f16x8*)(bp[i] + (ks + 3) * 512);
      }
    }
#pragma unroll
    for (int i = 0; i < 3; ++i) {
      int hh = hu[i], sec = su[i], strip = stu[i];
      _Float16* dq = sQ0 + hh * 4096;
      _Float16* dk = sK0 + hh * 4096;
      _Float16* dv = sVT0 + hh * 4096;
#pragma unroll
      for (int rt = 0; rt < 4; ++rt)
#pragma unroll
        for (int rg = 0; rg < 4; ++rg) {
          int row = rt * 16 + lg * 4 + rg;
          int col = strip * 16 + lr;
          _Float16 v = (_Float16)acc[i][rt][rg];
          if (sec == 0) dq[swz64(row, col)] = v;
          else if (sec == 1) dk[swz64(row, col)] = v;
          else dv[swz64(col, row)] = v;
        }
    }
    __syncthreads();
    {
      const int hh = wid >> 2;
      const int rs = wid & 3;
      const _Float16* mQ = sQ0 + hh * 4096;
      const _Float16* mK = sK0 + hh * 4096;
      const _Float16* mV = sVT0 + hh * 4096;
      _Float16* mP = sPO0 + hh * 4096;
      f32x4 sacc[4];
#pragma unroll
      for (int nt = 0; nt < 4; ++nt) sacc[nt] = zero4;
#pragma unroll
      for (int ks = 0; ks < 2; ++ks) {
        f16x8 afq = *(const f16x8*)&mQ[swz64(rs * 16 + lr, ks * 32 + lg * 8)];
#pragma unroll
        for (int nt = 0; nt < 4; ++nt) {
          f16x8 bfk = *(const f16x8*)&mK[swz64(nt * 16 + lr, ks * 32 + lg * 8)];
          sacc[nt] = MFMA16(afq, bfk, sacc[nt]);
        }
      }
      float p2[4][4];
#pragma unroll
      for (int rg = 0; rg < 4; ++rg) {
        int row = rs * 16 + lg * 4 + rg;
        float m = -1e30f;
#pragma unroll
        for (int nt = 0; nt < 4; ++nt) {
          int col = nt * 16 + lr;
          float v = (col <= row) ? sacc[nt][rg] : -1e30f;
          m = fmaxf(m, v);
        }
#pragma unroll
        for (int off = 8; off >= 1; off >>= 1) m = fmaxf(m, __shfl_xor(m, off));
        float e[4], s1 = 0.f;
#pragma unroll
        for (int nt = 0; nt < 4; ++nt) {
          int col = nt * 16 + lr;
          e[nt] = (col <= row) ? __expf(sacc[nt][rg] - m) : 0.f;
          s1 += e[nt];
        }
#pragma unroll
        for (int off = 8; off >= 1; off >>= 1) s1 += __shfl_xor(s1, off);
        float inv1 = 1.f / s1;
        float e2[4], s2 = 0.f;
#pragma unroll
        for (int nt = 0; nt < 4; ++nt) {
          e2[nt] = __expf(e[nt] * inv1);
          s2 += e2[nt];
        }
#pragma unroll
        for (int off = 8; off >= 1; off >>= 1) s2 += __shfl_xor(s2, off);
        float inv2 = 1.f / s2;
#pragma unroll
        for (int nt = 0; nt < 4; ++nt) p2[nt][rg] = e2[nt] * inv2;
      }
#pragma unroll
      for (int nt = 0; nt < 4; ++nt)
#pragma unroll
        for (int rg = 0; rg < 4; ++rg)
          mP[swz64(rs * 16 + lg * 4 + rg, nt * 16 + lr)] = (_Float16)p2[nt][rg];
      asm volatile("" ::: "memory");
      f32x4 oacc[4];
#pragma unroll
      for (int nt = 0; nt < 4; ++nt) oacc[nt] = zero4;
#pragma unroll
      for (int ks = 0; ks < 2; ++ks) {
        f16x8 afp = *(const f16x8*)&mP[swz64(rs * 16 + lr, ks * 32 + lg * 8)];
#pragma unroll
        for (int nt = 0; nt < 4; ++nt) {
          f16x8 bfv = *(const f16x8*)&mV[swz64(nt * 16 + lr, ks * 32 + lg * 8)];
          oacc[nt] = MFMA16(afp, bfv, oacc[nt]);
        }
      }
      asm volatile("" ::: "memory");
#pragma unroll
      for (int nt = 0; nt < 4; ++nt)
#pragma unroll
        for (int rg = 0; rg < 4; ++rg)
          mP[swz64(rs * 16 + lg * 4 + rg, nt * 16 + lr)] = (_Float16)oacc[nt][rg];
    }
    __syncthreads();
    {
      f16x8 bfC[2][4], afC[2][4];
#pragma unroll
      for (int rt = 0; rt < 4; ++rt)
        afC[0][rt] = *(const f16x8*)&sPO0[swz64(rt * 16 + lr, lg * 8)];
#pragma unroll
      for (int nt = 0; nt < 4; ++nt)
        bfC[0][nt] = *(const f16x8*)(wprojP + (size_t)(wid * 4 + nt) * 8192 +
                                     (size_t)(hp * 4) * 512 + lane * 8);
#pragma unroll
      for (int g = 0; g < 4; ++g) {
        if (g < 3) {
          int hn = (g + 1) >> 1, kn = (g + 1) & 1;
#pragma unroll
          for (int rt = 0; rt < 4; ++rt)
            afC[(g + 1) & 1][rt] = *(const f16x8*)&sPO0[hn * 4096 +
                swz64(rt * 16 + lr, kn * 32 + lg * 8)];
#pragma unroll
          for (int nt = 0; nt < 4; ++nt)
            bfC[(g + 1) & 1][nt] =
                *(const f16x8*)(wprojP + (size_t)(wid * 4 + nt) * 8192 +
                                (size_t)(hp * 4 + g + 1) * 512 + lane * 8);
        }
#pragma unroll
        for (int nt = 0; nt < 4; ++nt)
#pragma unroll
          for (int rt = 0; rt < 4; ++rt)
            accO[rt][nt] = MFMA16(afC[g & 1][rt], bfC[g & 1][nt], accO[rt][nt]);
      }
    }
  }
  __syncthreads();
  float bias_r[4];
#pragma unroll
  for (int nt = 0; nt < 4; ++nt) bias_r[nt] = bproj[wid * 64 + nt * 16 + lr];
  float* sEp = (float*)&sHeads[0][0][0];
  size_t base = (size_t)blockIdx.x * 32768;
#pragma unroll
  for (int half = 0; half < 2; ++half) {
#pragma unroll
    for (int rr = 0; rr < 2; ++rr) {
      int rt = half * 2 + rr;
#pragma unroll
      for (int nt = 0; nt < 4; ++nt)
#pragma unroll
        for (int rg = 0; rg < 4; ++rg) {
          int r = rr * 16 + lg * 4 + rg;
          int c = wid * 64 + nt * 16 + lr;
          sEp[r * 512 + (c ^ (((r >> 2) & 1) << 4))] = accO[rt][nt][rg] + bias_r[nt];
        }
    }
    __syncthreads();
#pragma unroll
    for (int j = 0; j < 8; ++j) {
      int f4 = tid + j * 512;
      int r = f4 >> 7;
      int c0 = (f4 & 127) << 2;
      float4 v = *(const float4*)&sEp[r * 512 + (c0 ^ (((r >> 2) & 1) << 4))];
      *(float4*)&out[base + (size_t)(half * 32 + r) * 512 + c0] = v;
    }
    if (half == 0) __syncthreads();
  }
}

extern "C" void kernel_launch(void* const* d_in, const int* in_sizes, int n_in,
                              void* d_out, int out_size, void* d_ws, size_t ws_size,
                              hipStream_t stream) {
  const float* x = (const float*)d_in[0];
  const float* Wqkv = (const float*)d_in[1];
  const float* Wproj = (const float*)d_in[2];
  const float* bproj = (const float*)d_in[3];
  float* out = (float*)d_out;

  const size_t W1 = 786432, W2 = 262144, XN = 33554432;
  const size_t QN = 100663296, HN = 33554432;
  _Float16* wqkvP = (_Float16*)d_ws;
  _Float16* wprojP = wqkvP + W1;
  _Float16* xP = wprojP + W2;
  _Float16* qkvP = xP + XN;
  _Float16* hP = qkvP + QN;
  const size_t NEED = (W1 + W2 + XN + QN + HN) * 2;

  prep_weights<<<dim3(4096), dim3(256), 0, stream>>>(Wqkv, Wproj, wqkvP, wprojP);
  if (ws_size >= NEED) {
    prep_x<<<dim3(1024), dim3(512), 0, stream>>>(x, xP);
    // Q,K cols: A = Wqkv^T rows 0..1023 (4 row-tiles), B = tokens (256 tiles)
    gemm8p<0><<<dim3(1024), dim3(512), 0, stream>>>(wqkvP, xP, qkvP, nullptr, nullptr, 4);
    // V cols: A = tokens (256 tiles), B = V weight rows (2 tiles)
    gemm8p<1><<<dim3(512), dim3(512), 0, stream>>>(xP, wqkvP + (size_t)64 * 8192,
                                                   qkvP, nullptr, nullptr, 256);
    attn_win<<<dim3(1024), dim3(512), 0, stream>>>(qkvP, hP);
    // proj: A = Wproj^T rows (2 tiles), B = tokens (256 tiles)
    gemm8p<2><<<dim3(512), dim3(512), 0, stream>>>(wprojP, hP, nullptr, out, bproj, 2);
  } else {
    attn_fused<<<dim3(1024), dim3(512), 0, stream>>>(x, wqkvP, wprojP, bproj, out);
  }
}